// Round 1
// baseline (354.026 us; speedup 1.0000x reference)
//
#include <hip/hip_runtime.h>
#include <cfloat>
#include <math.h>

#define BSZ 8
#define MROWS 64
#define NCOLS 4096
#define KSEL 32
#define EPSF 1e-20f

// One block per (b, m) row. Compute perturbed logits into LDS, select top-32
// by iterative argmax (tie-break: lower index, matching top_k stability),
// sort ascending, scatter 1.0f into the pre-zeroed output.
__global__ __launch_bounds__(256) void topk_scatter_kernel(
    const float* __restrict__ logits,   // (M, N)
    const float* __restrict__ u,        // (BS, M, N)
    float* __restrict__ out)            // (BS, M, K, N) pre-zeroed
{
    __shared__ float vals[NCOLS];
    __shared__ float wv[4];
    __shared__ int   wi[4];
    __shared__ int   sel[KSEL];

    const int r   = blockIdx.x;            // 0 .. BS*M-1
    const int m   = r & (MROWS - 1);
    const int tid = threadIdx.x;

    const float* lrow = logits + (size_t)m * NCOLS;
    const float* urow = u + (size_t)r * NCOLS;

    // Stage perturbed row into LDS (coalesced: lane i -> col i).
    for (int n = tid; n < NCOLS; n += 256) {
        float uu = urow[n];
        float gn = -0.001f * logf(-logf(uu + EPSF) + EPSF);
        vals[n] = lrow[n] + gn;
    }
    __syncthreads();

    const int lane = tid & 63;
    const int wave = tid >> 6;

    for (int it = 0; it < KSEL; ++it) {
        // Local scan: 16 strided LDS reads per thread (bank-conflict free).
        float bv = -FLT_MAX;
        int   bi = -1;
        for (int n = tid; n < NCOLS; n += 256) {
            float v = vals[n];
            if (v > bv || (v == bv && n < bi)) { bv = v; bi = n; }
        }
        // Wave (64-lane) butterfly reduce, no barriers.
        #pragma unroll
        for (int off = 32; off > 0; off >>= 1) {
            float ov = __shfl_xor(bv, off);
            int   oi = __shfl_xor(bi, off);
            if (ov > bv || (ov == bv && oi < bi)) { bv = ov; bi = oi; }
        }
        if (lane == 0) { wv[wave] = bv; wi[wave] = bi; }
        __syncthreads();
        if (tid == 0) {
            float fv = wv[0]; int fi = wi[0];
            #pragma unroll
            for (int w = 1; w < 4; ++w) {
                if (wv[w] > fv || (wv[w] == fv && wi[w] < fi)) { fv = wv[w]; fi = wi[w]; }
            }
            sel[it]  = fi;
            vals[fi] = -FLT_MAX;   // remove from next round
        }
        __syncthreads();
    }

    // Sort the 32 selected indices ascending (single thread, tiny).
    if (tid == 0) {
        for (int i = 1; i < KSEL; ++i) {
            int key = sel[i];
            int j = i - 1;
            while (j >= 0 && sel[j] > key) { sel[j + 1] = sel[j]; --j; }
            sel[j + 1] = key;
        }
    }
    __syncthreads();

    // Scatter the ones: row (b, m, j) gets a 1.0 at column sel[j].
    if (tid < KSEL) {
        size_t base = ((size_t)r * KSEL + tid) * (size_t)NCOLS;
        out[base + (size_t)sel[tid]] = 1.0f;
    }
}

extern "C" void kernel_launch(void* const* d_in, const int* in_sizes, int n_in,
                              void* d_out, int out_size, void* d_ws, size_t ws_size,
                              hipStream_t stream) {
    const float* logits = (const float*)d_in[0];   // (64, 4096) fp32
    const float* u      = (const float*)d_in[1];   // (8, 64, 4096) fp32
    float* out          = (float*)d_out;           // (8, 64, 32, 4096) fp32

    // Output is poisoned to 0xAA before every launch — zero it (mandatory work).
    hipMemsetAsync(out, 0, (size_t)out_size * sizeof(float), stream);

    topk_scatter_kernel<<<BSZ * MROWS, 256, 0, stream>>>(logits, u, out);
}

// Round 2
// 317.180 us; speedup vs baseline: 1.1162x; 1.1162x over previous
//
#include <hip/hip_runtime.h>
#include <math.h>

#define BSZ 8
#define MROWS 64
#define NCOLS 4096
#define KSEL 32
#define EPSF 1e-20f
#define NEG_INF (-3.402823466e+38f)

// One block per (b,m) row. Each of the 4 waves redundantly computes the
// top-32 selection from its own private LDS copy (no cross-wave sync in the
// hot loop), then the waves split the 32x4096 one-hot output write 8 k-rows
// each. Output fully written by this kernel (no memset needed).
//
// LDS layout per wave: 4096 floats, column col stored at
//   (col & ~63) | ((col + (col>>6)) & 63)
// (rotate-by-chunk swizzle). Lane l owns chunk [64l, 64l+64). This makes
// BOTH the per-lane chunk scan and the all-lanes single-chunk rescan
// 2-lanes-per-bank (free on gfx950, m136).
__global__ __launch_bounds__(256) void topk_onehot_kernel(
    const float* __restrict__ logits,   // (64, 4096)
    const float* __restrict__ u,        // (8, 64, 4096)
    float* __restrict__ out)            // (8, 64, 32, 4096)
{
    __shared__ float vals[4][NCOLS];    // 64 KiB total

    const int r    = blockIdx.x;        // row = b*64 + m, 0..511
    const int m    = r & (MROWS - 1);
    const int tid  = threadIdx.x;
    const int lane = tid & 63;
    const int w    = tid >> 6;

    float* vw = vals[w];

    const float4* u4 = (const float4*)(u + (size_t)r * NCOLS);
    const float4* l4 = (const float4*)(logits + (size_t)m * NCOLS);

    // ---- Stage perturbed row into this wave's swizzled LDS copy ----
    #pragma unroll
    for (int c = 0; c < 16; ++c) {
        int q = (c << 6) + lane;                 // float4 index, coalesced
        float4 uu = u4[q];
        float4 lg = l4[q];
        float px = lg.x - 0.001f * logf(-logf(uu.x + EPSF) + EPSF);
        float py = lg.y - 0.001f * logf(-logf(uu.y + EPSF) + EPSF);
        float pz = lg.z - 0.001f * logf(-logf(uu.z + EPSF) + EPSF);
        float pw = lg.w - 0.001f * logf(-logf(uu.w + EPSF) + EPSF);
        int col   = q << 2;
        int chunk = col >> 6;                    // same chunk for all 4 cols
        int base  = chunk << 6;
        vw[base + ((col + 0 + chunk) & 63)] = px;
        vw[base + ((col + 1 + chunk) & 63)] = py;
        vw[base + ((col + 2 + chunk) & 63)] = pz;
        vw[base + ((col + 3 + chunk) & 63)] = pw;
    }
    __syncthreads();   // cross-lane LDS visibility (staging is cross-lane)

    // ---- Initial per-lane scan of own chunk (conflict-free) ----
    float lmax = NEG_INF;
    int   lidx = 0x7FFFFFFF;
    {
        const int cb = lane << 6;
        #pragma unroll 8
        for (int c = 0; c < 64; ++c) {           // ascending col => low-idx ties
            float v = vw[cb + ((c + lane) & 63)];
            if (v > lmax) { lmax = v; lidx = cb + c; }
        }
    }

    // ---- 32 iterative argmax selections, wave-local, no barriers ----
    unsigned long long removed = 0ull;           // removal mask for OWN chunk
    int sel_reg = 0x7FFFFFFF;                    // lane i (<32) holds winner i
    for (int it = 0; it < KSEL; ++it) {
        float bv = lmax; int bi = lidx;
        #pragma unroll
        for (int off = 32; off; off >>= 1) {
            float ov = __shfl_xor(bv, off);
            int   oi = __shfl_xor(bi, off);
            if (ov > bv || (ov == bv && oi < bi)) { bv = ov; bi = oi; }
        }
        if (lane == it) sel_reg = bi;

        const int wl = bi >> 6;                  // winner chunk / owner lane
        if (lane == wl) removed |= (1ull << (bi & 63));

        // Cooperative rescan of chunk wl: lane j handles element j.
        unsigned long long rm = __shfl(removed, wl);
        float nv = vw[(wl << 6) + ((lane + wl) & 63)];
        int   ni = (wl << 6) + lane;
        if ((rm >> lane) & 1ull) nv = NEG_INF;
        #pragma unroll
        for (int off = 32; off; off >>= 1) {
            float ov = __shfl_xor(nv, off);
            int   oi = __shfl_xor(ni, off);
            if (ov > nv || (ov == nv && oi < ni)) { nv = ov; ni = oi; }
        }
        if (lane == wl) { lmax = nv; lidx = ni; }
    }

    // ---- Rank (= sorted-ascending position) via shuffles; overlay into LDS ----
    int myw = sel_reg;
    int rank = 0;
    #pragma unroll
    for (int j = 0; j < KSEL; ++j) {
        int wj = __shfl(sel_reg, j);             // winners are distinct
        rank += (wj < myw) ? 1 : 0;
    }
    int* si = (int*)vw;                          // vals LDS is free now
    if (lane < KSEL) si[rank] = myw;
    __syncthreads();                             // visibility before write phase

    // ---- Write phase: wave w writes k-rows [8w, 8w+8) of this row ----
    #pragma unroll 2
    for (int jj = 0; jj < 8; ++jj) {
        int j  = (w << 3) + jj;
        int t  = si[j];                          // broadcast read
        int tq = t >> 2;
        int te = t & 3;
        float4* orow = (float4*)(out + (size_t)(r * KSEL + j) * NCOLS);
        #pragma unroll
        for (int c = 0; c < 16; ++c) {
            int q = (c << 6) + lane;             // 1 KiB/instr coalesced
            bool hit = (q == tq);
            float4 z;
            z.x = (hit && te == 0) ? 1.0f : 0.0f;
            z.y = (hit && te == 1) ? 1.0f : 0.0f;
            z.z = (hit && te == 2) ? 1.0f : 0.0f;
            z.w = (hit && te == 3) ? 1.0f : 0.0f;
            orow[q] = z;
        }
    }
}

extern "C" void kernel_launch(void* const* d_in, const int* in_sizes, int n_in,
                              void* d_out, int out_size, void* d_ws, size_t ws_size,
                              hipStream_t stream) {
    const float* logits = (const float*)d_in[0];   // (64, 4096) fp32
    const float* u      = (const float*)d_in[1];   // (8, 64, 4096) fp32
    float* out          = (float*)d_out;           // (8, 64, 32, 4096) fp32

    topk_onehot_kernel<<<BSZ * MROWS, 256, 0, stream>>>(logits, u, out);
}

// Round 3
// 307.811 us; speedup vs baseline: 1.1501x; 1.0304x over previous
//
#include <hip/hip_runtime.h>
#include <math.h>

#define BSZ 8
#define MROWS 64
#define NCOLS 4096
#define KSEL 32
#define EPSF 1e-20f
#define NEG_INF (-3.402823466e+38f)

// ---------------------------------------------------------------------------
// Kernel 1: per-(b,m)-row top-32 selection. One block per row; 4 waves stage
// the perturbed row into a swizzled 16 KiB LDS buffer; wave 0 then does 32
// iterative argmax selections (barrier-free: LDS is read-only after staging,
// removals tracked in per-lane register masks), ranks them ascending, and
// writes the 32 sorted indices to idx_out[r*32 ..].
//
// Swizzle: column col lives at (col & ~63) | ((col + (col>>6)) & 63).
// Lane l owns chunk [64l, 64l+64). Both the per-lane chunk scan and the
// all-lanes single-chunk rescan are 2-lanes-per-bank (free on gfx950, m136).
// ---------------------------------------------------------------------------
__global__ __launch_bounds__(256) void topk_select_kernel(
    const float* __restrict__ logits,   // (64, 4096)
    const float* __restrict__ u,        // (8, 64, 4096)
    int* __restrict__ idx_out)          // (512, 32)
{
    __shared__ float vals[NCOLS];       // 16 KiB

    const int r   = blockIdx.x;         // row = b*64 + m
    const int m   = r & (MROWS - 1);
    const int tid = threadIdx.x;

    const float4* u4 = (const float4*)(u + (size_t)r * NCOLS);
    const float4* l4 = (const float4*)(logits + (size_t)m * NCOLS);

    // ---- Cooperative staging: 256 threads x 4 float4 = 4096 elements ----
    #pragma unroll
    for (int c = 0; c < 4; ++c) {
        int q = (c << 8) + tid;                  // float4 index, coalesced
        float4 uu = u4[q];
        float4 lg = l4[q];
        float px = lg.x - 0.001f * logf(-logf(uu.x + EPSF) + EPSF);
        float py = lg.y - 0.001f * logf(-logf(uu.y + EPSF) + EPSF);
        float pz = lg.z - 0.001f * logf(-logf(uu.z + EPSF) + EPSF);
        float pw = lg.w - 0.001f * logf(-logf(uu.w + EPSF) + EPSF);
        int col   = q << 2;
        int chunk = col >> 6;                    // same chunk for all 4 cols
        int base  = chunk << 6;
        vals[base + ((col + 0 + chunk) & 63)] = px;
        vals[base + ((col + 1 + chunk) & 63)] = py;
        vals[base + ((col + 2 + chunk) & 63)] = pz;
        vals[base + ((col + 3 + chunk) & 63)] = pw;
    }
    __syncthreads();

    if (tid >= 64) return;                       // wave 0 only from here
    const int lane = tid;

    // ---- Initial per-lane scan of own chunk ----
    float lmax = NEG_INF;
    int   lidx = 0x7FFFFFFF;
    {
        const int cb = lane << 6;
        #pragma unroll 8
        for (int c = 0; c < 64; ++c) {           // ascending col => low-idx ties
            float v = vals[cb + ((c + lane) & 63)];
            if (v > lmax) { lmax = v; lidx = cb + c; }
        }
    }

    // ---- 32 iterative argmax selections, barrier-free ----
    unsigned long long removed = 0ull;           // removal mask for OWN chunk
    int sel_reg = 0x7FFFFFFF;                    // lane i (<32) holds winner i
    for (int it = 0; it < KSEL; ++it) {
        float bv = lmax; int bi = lidx;
        #pragma unroll
        for (int off = 32; off; off >>= 1) {
            float ov = __shfl_xor(bv, off);
            int   oi = __shfl_xor(bi, off);
            if (ov > bv || (ov == bv && oi < bi)) { bv = ov; bi = oi; }
        }
        if (lane == it) sel_reg = bi;

        const int wl = bi >> 6;                  // winner chunk / owner lane
        if (lane == wl) removed |= (1ull << (bi & 63));

        // Cooperative rescan of chunk wl: lane j handles element j.
        unsigned long long rm = __shfl(removed, wl);
        float nv = vals[(wl << 6) + ((lane + wl) & 63)];
        int   ni = (wl << 6) + lane;
        if ((rm >> lane) & 1ull) nv = NEG_INF;
        #pragma unroll
        for (int off = 32; off; off >>= 1) {
            float ov = __shfl_xor(nv, off);
            int   oi = __shfl_xor(ni, off);
            if (ov > nv || (ov == nv && oi < ni)) { nv = ov; ni = oi; }
        }
        if (lane == wl) { lmax = nv; lidx = ni; }
    }

    // ---- Rank = ascending position (winners are distinct) ----
    int myw = sel_reg;
    int rank = 0;
    #pragma unroll
    for (int j = 0; j < KSEL; ++j) {
        int wj = __shfl(sel_reg, j);
        rank += (wj < myw) ? 1 : 0;
    }
    if (lane < KSEL) idx_out[r * KSEL + rank] = myw;
}

// ---------------------------------------------------------------------------
// Kernel 2: pure streaming one-hot writer. No LDS, tiny VGPR -> full
// occupancy. One wave per k-row (16 KiB): 16 coalesced float4 stores/lane.
// ---------------------------------------------------------------------------
__global__ __launch_bounds__(256) void onehot_write_kernel(
    const int* __restrict__ idx,        // (16384)
    float* __restrict__ out)            // (16384, 4096)
{
    const int rho  = (blockIdx.x << 2) | (threadIdx.x >> 6);  // global k-row
    const int lane = threadIdx.x & 63;

    const int t  = idx[rho];            // wave-uniform broadcast load
    const int tq = t >> 2;
    const int te = t & 3;

    float4* orow = (float4*)(out + (size_t)rho * NCOLS);
    #pragma unroll
    for (int c = 0; c < 16; ++c) {
        int q = (c << 6) + lane;        // 1 KiB/instr per wave, coalesced
        bool hit = (q == tq);
        float4 z;
        z.x = (hit && te == 0) ? 1.0f : 0.0f;
        z.y = (hit && te == 1) ? 1.0f : 0.0f;
        z.z = (hit && te == 2) ? 1.0f : 0.0f;
        z.w = (hit && te == 3) ? 1.0f : 0.0f;
        orow[q] = z;
    }
}

extern "C" void kernel_launch(void* const* d_in, const int* in_sizes, int n_in,
                              void* d_out, int out_size, void* d_ws, size_t ws_size,
                              hipStream_t stream) {
    const float* logits = (const float*)d_in[0];   // (64, 4096) fp32
    const float* u      = (const float*)d_in[1];   // (8, 64, 4096) fp32
    float* out          = (float*)d_out;           // (8, 64, 32, 4096) fp32
    int*   idx          = (int*)d_ws;              // 16384 ints of scratch

    topk_select_kernel<<<BSZ * MROWS, 256, 0, stream>>>(logits, u, idx);
    onehot_write_kernel<<<(BSZ * MROWS * KSEL) / 4, 256, 0, stream>>>(idx, out);
}

// Round 4
// 273.162 us; speedup vs baseline: 1.2960x; 1.1268x over previous
//
#include <hip/hip_runtime.h>
#include <math.h>

#define BSZ 8
#define MROWS 64
#define NCOLS 4096
#define KSEL 32
#define EPSF 1e-20f
#define NEG_INF (-3.402823466e+38f)

// One block per (b,m) row. Phases:
//   A) all 4 waves stage perturbed row into swizzled LDS (32 logf/thread)
//   B) wave 0: barrier-free iterative top-32 + rank  (runs ~8us)
//      waves 1-3: concurrently stream zeros into k-rows 5..31 (~40us)
//   C) wave 0 writes k-rows 0..4 with inline one-hot (balances its late start)
//   D) barrier; lanes 5..31 scatter the remaining 27 ones over the zeros.
//
// Swizzle: column col lives at (col & ~63) | ((col + (col>>6)) & 63).
// Lane l owns chunk [64l, 64l+64). Per-lane chunk scan and all-lanes
// single-chunk rescan are both 2-lanes-per-bank (free on gfx950, m136).
__global__ __launch_bounds__(256) void topk_fused_kernel(
    const float* __restrict__ logits,   // (64, 4096)
    const float* __restrict__ u,        // (8, 64, 4096)
    float* __restrict__ out)            // (8, 64, 32, 4096)
{
    __shared__ float vals[NCOLS];       // 16 KiB
    __shared__ int   si[KSEL];

    const int r   = blockIdx.x;         // row = b*64 + m
    const int m   = r & (MROWS - 1);
    const int tid = threadIdx.x;

    const float4* u4 = (const float4*)(u + (size_t)r * NCOLS);
    const float4* l4 = (const float4*)(logits + (size_t)m * NCOLS);

    // ---- Phase A: cooperative staging (256 threads x 4 float4) ----
    #pragma unroll
    for (int c = 0; c < 4; ++c) {
        int q = (c << 8) + tid;                  // float4 index, coalesced
        float4 uu = u4[q];
        float4 lg = l4[q];
        float px = lg.x - 0.001f * logf(-logf(uu.x + EPSF) + EPSF);
        float py = lg.y - 0.001f * logf(-logf(uu.y + EPSF) + EPSF);
        float pz = lg.z - 0.001f * logf(-logf(uu.z + EPSF) + EPSF);
        float pw = lg.w - 0.001f * logf(-logf(uu.w + EPSF) + EPSF);
        int col   = q << 2;
        int chunk = col >> 6;                    // same chunk for all 4 cols
        int base  = chunk << 6;
        vals[base + ((col + 0 + chunk) & 63)] = px;
        vals[base + ((col + 1 + chunk) & 63)] = py;
        vals[base + ((col + 2 + chunk) & 63)] = pz;
        vals[base + ((col + 3 + chunk) & 63)] = pw;
    }
    __syncthreads();

    const int lane = tid & 63;
    const int w    = tid >> 6;
    float* orow0   = out + (size_t)r * KSEL * NCOLS;

    if (w == 0) {
        // ---- Phase B (wave 0): selection ----
        float lmax = NEG_INF;
        int   lidx = 0x7FFFFFFF;
        {
            const int cb = lane << 6;
            #pragma unroll 8
            for (int c = 0; c < 64; ++c) {       // ascending col => low-idx ties
                float v = vals[cb + ((c + lane) & 63)];
                if (v > lmax) { lmax = v; lidx = cb + c; }
            }
        }
        unsigned long long removed = 0ull;       // removal mask for OWN chunk
        int sel_reg = 0x7FFFFFFF;                // lane i (<32) holds winner i
        for (int it = 0; it < KSEL; ++it) {
            float bv = lmax; int bi = lidx;
            #pragma unroll
            for (int off = 32; off; off >>= 1) {
                float ov = __shfl_xor(bv, off);
                int   oi = __shfl_xor(bi, off);
                if (ov > bv || (ov == bv && oi < bi)) { bv = ov; bi = oi; }
            }
            if (lane == it) sel_reg = bi;

            const int wl = bi >> 6;              // winner chunk / owner lane
            if (lane == wl) removed |= (1ull << (bi & 63));

            unsigned long long rm = __shfl(removed, wl);
            float nv = vals[(wl << 6) + ((lane + wl) & 63)];
            int   ni = (wl << 6) + lane;
            if ((rm >> lane) & 1ull) nv = NEG_INF;
            #pragma unroll
            for (int off = 32; off; off >>= 1) {
                float ov = __shfl_xor(nv, off);
                int   oi = __shfl_xor(ni, off);
                if (ov > nv || (ov == nv && oi < ni)) { nv = ov; ni = oi; }
            }
            if (lane == wl) { lmax = nv; lidx = ni; }
        }
        // rank = ascending position (winners distinct)
        int myw = sel_reg;
        int rank = 0;
        #pragma unroll
        for (int j = 0; j < KSEL; ++j) {
            int wj = __shfl(sel_reg, j);
            rank += (wj < myw) ? 1 : 0;
        }
        if (lane < KSEL) si[rank] = myw;         // same-wave DS pipe: in-order

        // ---- Phase C (wave 0): k-rows 0..4 with inline one-hot ----
        for (int j = 0; j < 5; ++j) {
            int t  = si[j];                      // same-wave LDS read, ordered
            int tq = t >> 2;
            int te = t & 3;
            float4* orow = (float4*)(orow0 + (size_t)j * NCOLS);
            #pragma unroll
            for (int c = 0; c < 16; ++c) {
                int q = (c << 6) + lane;
                bool hit = (q == tq);
                float4 z;
                z.x = (hit && te == 0) ? 1.0f : 0.0f;
                z.y = (hit && te == 1) ? 1.0f : 0.0f;
                z.z = (hit && te == 2) ? 1.0f : 0.0f;
                z.w = (hit && te == 3) ? 1.0f : 0.0f;
                orow[q] = z;
            }
        }
    } else {
        // ---- Phase B (waves 1-3): zero-fill k-rows 5..31, 9 rows each ----
        const int start = 5 + (w - 1) * 9;
        const float4 z4 = make_float4(0.f, 0.f, 0.f, 0.f);
        for (int j = start; j < start + 9; ++j) {
            float4* orow = (float4*)(orow0 + (size_t)j * NCOLS);
            #pragma unroll
            for (int c = 0; c < 16; ++c) orow[(c << 6) + lane] = z4;
        }
    }

    __syncthreads();   // zeros drained + si visible

    // ---- Phase D: scatter the 27 remaining ones ----
    if (tid >= 5 && tid < KSEL) {
        orow0[(size_t)tid * NCOLS + (size_t)si[tid]] = 1.0f;
    }
}

extern "C" void kernel_launch(void* const* d_in, const int* in_sizes, int n_in,
                              void* d_out, int out_size, void* d_ws, size_t ws_size,
                              hipStream_t stream) {
    const float* logits = (const float*)d_in[0];   // (64, 4096) fp32
    const float* u      = (const float*)d_in[1];   // (8, 64, 4096) fp32
    float* out          = (float*)d_out;           // (8, 64, 32, 4096) fp32

    topk_fused_kernel<<<BSZ * MROWS, 256, 0, stream>>>(logits, u, out);
}